// Round 6
// baseline (37746.381 us; speedup 1.0000x reference)
//
#include <hip/hip_runtime.h>
#include <stdint.h>
#include <stddef.h>

typedef unsigned int u32;
typedef unsigned short u16;
typedef __attribute__((ext_vector_type(4))) float f32x4;
typedef __attribute__((ext_vector_type(4))) u32 u32x4;

#define TT 500
#define TCH 100                   // time chunk for wx
#define NCH 5
#define M_CH (128 * TCH)          // chunk row space: mm = r*TCH + tt, r in [0,128)

// ws layout: wx f32 [128*TCH][1024] @0 (52,428,800 B)
//            hsA u16 [128][500][512] @52,428,800 (65,536,000 B)
//            hsB u16 [128][500][512] @117,964,800 (65,536,000 B)   total 183.5 MB
#define OFF_HSA 52428800ull
#define OFF_HSB 117964800ull

__device__ __forceinline__ float bf2f(u16 u) {
  union { u32 i; float f; } v; v.i = ((u32)u) << 16; return v.f;
}
__device__ __forceinline__ u16 f2bf(float f) {
  union { float f; u32 i; } v; v.f = f;
  u32 x = v.i;
  return (u16)((x + 0x7FFFu + ((x >> 16) & 1u)) >> 16);   // RNE
}

// ---------------- wx GEMM (fp32 compute, LDS-tiled 64x64, direct gather) ------
// MODE 0: A = batch f32 [64][500][89], K=89.
// MODE 1: A = hs_in bf16 [128][500][512], K=1024 (bidir concat gather).
// W native f32 [K][1024]. wx out: [M_CH][1024] f32, row mm = r*TCH + tt.
template <int MODE>
__global__ __launch_bounds__(256) void wx_gemm_f32(const float* __restrict__ Af,
                                                   const u16* __restrict__ Ab,
                                                   const float* __restrict__ W,
                                                   float* __restrict__ wx, int t0) {
  constexpr int K = (MODE == 0) ? 89 : 1024;
  __shared__ float As[16][68];   // [k][row]
  __shared__ float Bs[16][68];   // [k][col]
  const int m0 = blockIdx.x * 64;
  const int n0 = blockIdx.y * 64;
  const int tid = threadIdx.x;
  const int tx = tid & 15, ty = tid >> 4;

  float acc[4][4];
#pragma unroll
  for (int i = 0; i < 4; ++i)
#pragma unroll
    for (int j = 0; j < 4; ++j) acc[i][j] = 0.f;

  for (int k0 = 0; k0 < K; k0 += 16) {
    // stage A: 64 rows x 16 k
#pragma unroll
    for (int i = 0; i < 4; ++i) {
      int idx = tid + i * 256;
      int ak = idx & 15, arow = idx >> 4;
      int mm = m0 + arow;
      int r = mm / TCH, tt = mm - r * TCH;
      int t = t0 + tt;
      int k = k0 + ak;
      float v = 0.f;
      if (MODE == 0) {
        int b = (r < 64) ? r : r - 64;
        int tr = (r < 64) ? t : 499 - t;
        if (k < 89) v = Af[((size_t)b * 500 + tr) * 89 + k];
      } else {
        int fr, ftt, br, btt;
        if (r < 64) { fr = r; ftt = t; br = 64 + r; btt = 499 - t; }
        else        { fr = r - 64; ftt = 499 - t; br = r; btt = t; }
        v = (k < 512) ? bf2f(Ab[((size_t)fr * 500 + ftt) * 512 + k])
                      : bf2f(Ab[((size_t)br * 500 + btt) * 512 + (k - 512)]);
      }
      As[ak][arow] = v;
    }
    // stage B: 16 k x 64 cols
#pragma unroll
    for (int i = 0; i < 4; ++i) {
      int idx = tid + i * 256;
      int bn = idx & 63, bk = idx >> 6;
      int k = k0 + bk;
      Bs[bk][bn] = (k < K) ? W[(size_t)k * 1024 + n0 + bn] : 0.f;
    }
    __syncthreads();
#pragma unroll
    for (int kk = 0; kk < 16; ++kk) {
      f32x4 a4 = *(const f32x4*)&As[kk][ty * 4];
      f32x4 b4 = *(const f32x4*)&Bs[kk][tx * 4];
#pragma unroll
      for (int i = 0; i < 4; ++i)
#pragma unroll
        for (int j = 0; j < 4; ++j) acc[i][j] = fmaf(a4[i], b4[j], acc[i][j]);
    }
    __syncthreads();
  }
#pragma unroll
  for (int i = 0; i < 4; ++i)
#pragma unroll
    for (int j = 0; j < 4; ++j)
      wx[(size_t)(m0 + ty * 4 + i) * 1024 + n0 + tx * 4 + j] = acc[i][j];
}

// ---------------- recurrence (fp32 VALU, communication-free) ------------------
// 64 blocks x 2 batch-rows each; a block owns the FULL h vector of its rows ->
// zero inter-block coupling. h in LDS (f32); U [512][1024] f32 streamed from
// L2 each step. Output h stored bf16 into hs_out (ping-pong vs the gemm input).
// Chunk-boundary reload comes from hs_out's own history (written by chunk c-1).
__global__ __launch_bounds__(1024) void rec_f32(const float* __restrict__ wx,
                                                const float* __restrict__ U,
                                                u16* __restrict__ hs_out, int t0) {
  __shared__ float hld[2][512];
  __shared__ float garr[2][1024];
  const int tid = threadIdx.x;      // 1024
  const int g = tid;                // gate column
  const int r0g = blockIdx.x * 2;   // global rows r0g, r0g+1
  {
    int r = tid >> 9, c = tid & 511;
    if (t0 == 0) hld[r][c] = 0.f;
    else         hld[r][c] = bf2f(hs_out[((size_t)(r0g + r) * 500 + (t0 - 1)) * 512 + c]);
  }
  __syncthreads();

  for (int tt = 0; tt < TCH; ++tt) {
    const int t = t0 + tt;
    float acc0 = wx[((size_t)(r0g    ) * TCH + tt) * 1024 + g];
    float acc1 = wx[((size_t)(r0g + 1) * TCH + tt) * 1024 + g];
#pragma unroll 4
    for (int k4 = 0; k4 < 128; ++k4) {
      f32x4 h0 = *(const f32x4*)&hld[0][k4 * 4];
      f32x4 h1 = *(const f32x4*)&hld[1][k4 * 4];
#pragma unroll
      for (int e = 0; e < 4; ++e) {
        float u = U[(size_t)(k4 * 4 + e) * 1024 + g];
        acc0 = fmaf(h0[e], u, acc0);
        acc1 = fmaf(h1[e], u, acc1);
      }
    }
    garr[0][g] = acc0;
    garr[1][g] = acc1;
    __syncthreads();
    {
      int r = tid >> 9, c = tid & 511;
      float a = garr[r][c], z = garr[r][512 + c];
      float zz = 1.f / (1.f + expf(-z));
      float hn = zz * hld[r][c] + (1.f - zz) * tanhf(a);
      hld[r][c] = hn;
      hs_out[((size_t)(r0g + r) * 500 + t) * 512 + c] = f2bf(hn);
    }
    __syncthreads();
  }
}

// ---------------- final FC (fp32 compute, bf16 h input) -----------------------
__global__ __launch_bounds__(256) void fc_f32(const u16* __restrict__ hs,
                                              const float* __restrict__ Wfc,
                                              const float* __restrict__ bfc,
                                              float* __restrict__ out) {
  __shared__ float rows[16][1024];
  const int tid = threadIdx.x;
  const int pair0 = blockIdx.x * 16;
  for (int c = tid; c < 2048; c += 256) {      // 2048 8-elem chunks = 16 x 128
    int p = c >> 7, chunk = c & 127;
    int pr = pair0 + p;
    int b = pr / 500, t = pr - b * 500;
    size_t off;
    if (chunk < 64) off = ((size_t)b * 500 + t) * 512 + (size_t)chunk * 8;
    else            off = ((size_t)(64 + b) * 500 + (499 - t)) * 512 + (size_t)(chunk - 64) * 8;
    u32x4 vh = *(const u32x4*)(hs + off);
    const u16* ph = (const u16*)&vh;
    float* dst = &rows[p][chunk * 8];
#pragma unroll
    for (int e = 0; e < 8; ++e) dst[e] = bf2f(ph[e]);
  }
  __syncthreads();
#pragma unroll
  for (int rep = 0; rep < 3; ++rep) {
    int oi = rep * 256 + tid;          // 640 = 16 pairs x 40 outs
    if (oi < 640) {
      int p = oi / 40, o = oi - p * 40;
      float acc = bfc[o];
#pragma unroll 8
      for (int gg = 0; gg < 1024; ++gg)
        acc = fmaf(rows[p][gg], Wfc[gg * 40 + o], acc);
      out[(size_t)(pair0 + p) * 40 + o] = acc;
    }
  }
}

// ---------------- launch ------------------------------------------------------
extern "C" void kernel_launch(void* const* d_in, const int* in_sizes, int n_in,
                              void* d_out, int out_size, void* d_ws, size_t ws_size,
                              hipStream_t stream) {
  const float* batch = (const float*)d_in[0];
  const float* W0 = (const float*)d_in[2];
  const float* U0 = (const float*)d_in[3];
  const float* W1 = (const float*)d_in[4];
  const float* U1 = (const float*)d_in[5];
  const float* W2 = (const float*)d_in[6];
  const float* U2 = (const float*)d_in[7];
  const float* Wfc = (const float*)d_in[8];
  const float* bfc = (const float*)d_in[9];
  float* out = (float*)d_out;

  char* ws = (char*)d_ws;
  float* wx = (float*)(ws);
  u16* hsA = (u16*)(ws + OFF_HSA);
  u16* hsB = (u16*)(ws + OFF_HSB);

  dim3 ggrid(M_CH / 64, 1024 / 64);

  // layer 0: gemm reads batch, rec writes hsA           (no read/write overlap)
  for (int c = 0; c < NCH; ++c) {
    wx_gemm_f32<0><<<ggrid, 256, 0, stream>>>(batch, (const u16*)nullptr, W0, wx, c * TCH);
    rec_f32<<<64, 1024, 0, stream>>>(wx, U0, hsA, c * TCH);
  }
  // layer 1: gemm reads hsA (layer-0 h), rec writes hsB (ping-pong, WAR-safe)
  for (int c = 0; c < NCH; ++c) {
    wx_gemm_f32<1><<<ggrid, 256, 0, stream>>>((const float*)nullptr, hsA, W1, wx, c * TCH);
    rec_f32<<<64, 1024, 0, stream>>>(wx, U1, hsB, c * TCH);
  }
  // layer 2: gemm reads hsB, rec writes hsA
  for (int c = 0; c < NCH; ++c) {
    wx_gemm_f32<1><<<ggrid, 256, 0, stream>>>((const float*)nullptr, hsB, W2, wx, c * TCH);
    rec_f32<<<64, 1024, 0, stream>>>(wx, U2, hsA, c * TCH);
  }
  fc_f32<<<2000, 256, 0, stream>>>(hsA, Wfc, bfc, out);
}